// Round 3
// baseline (302.116 us; speedup 1.0000x reference)
//
#include <hip/hip_runtime.h>
#include <hip/hip_fp16.h>
#include <math.h>

#define N_NODES 50000
#define N_EDGES 800000
#define F_IN    128
#define D_HID   96
#define NHEAD   8
#define DH      12
#define N_CLS   40
#define NEG_SLOPE 0.2f

#define NPART   (N_NODES / 8)        // 6250 dst nodes per XCD group
#define ECHUNK  (N_EDGES / 32)       // 25000 edges per block within a group

// ---------------- CSR build (XCD-partitioned by dst range) ----------------
// 256 blocks: group g = blockIdx&7 owns dst in [g*NPART,(g+1)*NPART);
// block w = blockIdx>>3 scans edge chunk [w*ECHUNK,(w+1)*ECHUNK).
__global__ __launch_bounds__(256) void hist_part_kernel(
    const int* __restrict__ edst, int* __restrict__ cnt)
{
    __shared__ int lcnt[NPART];
    for (int i = threadIdx.x; i < NPART; i += 256) lcnt[i] = 0;
    __syncthreads();
    int lo = (blockIdx.x & 7) * NPART;
    int e0 = (blockIdx.x >> 3) * ECHUNK;
    for (int e = e0 + threadIdx.x; e < e0 + ECHUNK; e += 256) {
        int d = edst[e] - lo;
        if ((unsigned)d < (unsigned)NPART) atomicAdd(&lcnt[d], 1);
    }
    __syncthreads();
    for (int i = threadIdx.x; i < NPART; i += 256) {
        int v = lcnt[i];
        if (v) atomicAdd(&cnt[lo + i], v);
    }
}

__global__ void scan1_kernel(const int* __restrict__ cnt, int* __restrict__ incl,
                             int* __restrict__ partials, int n) {
    __shared__ int sdata[256];
    int t = threadIdx.x;
    int base = blockIdx.x * 1024 + t * 4;
    int v[4];
#pragma unroll
    for (int j = 0; j < 4; j++) { int i = base + j; v[j] = (i < n) ? cnt[i] : 0; }
    v[1] += v[0]; v[2] += v[1]; v[3] += v[2];
    sdata[t] = v[3];
    __syncthreads();
    for (int off = 1; off < 256; off <<= 1) {
        int x = (t >= off) ? sdata[t - off] : 0;
        __syncthreads();
        sdata[t] += x;
        __syncthreads();
    }
    int excl = sdata[t] - v[3];
#pragma unroll
    for (int j = 0; j < 4; j++) { int i = base + j; if (i < n) incl[i] = v[j] + excl; }
    if (t == 255) partials[blockIdx.x] = sdata[255];
}

__global__ void scan2_kernel(int* partials, int nb) {
    if (threadIdx.x == 0 && blockIdx.x == 0) {
        int run = 0;
        for (int i = 0; i < nb; i++) { int v = partials[i]; partials[i] = run; run += v; }
    }
}

__global__ void scan3_kernel(const int* __restrict__ cnt, int* __restrict__ incl_cursor,
                             const int* __restrict__ partials, int* __restrict__ rowptr, int n) {
    int i = blockIdx.x * blockDim.x + threadIdx.x;
    if (i >= n) return;
    int v = incl_cursor[i] + partials[i >> 10];
    rowptr[i + 1] = v;
    incl_cursor[i] = v - cnt[i];
    if (i == 0) rowptr[0] = 0;
}

__global__ __launch_bounds__(256) void fill_part_kernel(
    const int* __restrict__ esrc, const int* __restrict__ edst,
    int* __restrict__ cursor, unsigned short* __restrict__ srclist)
{
    int lo = (blockIdx.x & 7) * NPART;
    int e0 = (blockIdx.x >> 3) * ECHUNK;
    for (int e = e0 + threadIdx.x; e < e0 + ECHUNK; e += 256) {
        int d = edst[e] - lo;
        if ((unsigned)d < (unsigned)NPART) {
            int p = atomicAdd(&cursor[lo + d], 1);
            srclist[p] = (unsigned short)esrc[e];
        }
    }
}

// ---------------- GEMM (A[M,K] @ W[K,96]) + per-head alpha epilogue ----------------
#define BM 64
#define BK 32
__global__ __launch_bounds__(256) void gemm_alpha_kernel(
    const float* __restrict__ A, const float* __restrict__ W,
    const float* __restrict__ asrc, const float* __restrict__ adst,
    __half* __restrict__ Hout, float* __restrict__ aS, float* __restrict__ aD,
    int M, int K)
{
    __shared__ float As[BM][BK + 1];
    __shared__ float Ws[BK][D_HID];
    int tid = threadIdx.x;
    int r   = tid & 31;
    int cg  = tid >> 5;           // head index 0..7
    int n0  = blockIdx.x * BM;

    float acc[2][12];
#pragma unroll
    for (int i = 0; i < 2; i++)
#pragma unroll
        for (int j = 0; j < 12; j++) acc[i][j] = 0.f;

    int wrow = tid >> 3;
    int wcol = (tid & 7) * 12;

    for (int k0 = 0; k0 < K; k0 += BK) {
        for (int idx = tid; idx < BM * BK; idx += 256) {
            int row = idx >> 5, col = idx & 31;
            int gr = n0 + row;
            As[row][col] = (gr < M) ? A[(size_t)gr * K + k0 + col] : 0.f;
        }
        {
            const float* wp = W + (size_t)(k0 + wrow) * D_HID + wcol;
#pragma unroll
            for (int j = 0; j < 12; j++) Ws[wrow][wcol + j] = wp[j];
        }
        __syncthreads();
#pragma unroll 8
        for (int kk = 0; kk < BK; kk++) {
            float4 w0 = *(const float4*)&Ws[kk][cg * 12];
            float4 w1 = *(const float4*)&Ws[kk][cg * 12 + 4];
            float4 w2 = *(const float4*)&Ws[kk][cg * 12 + 8];
            float a0 = As[r][kk];
            float a1 = As[r + 32][kk];
            acc[0][0] += a0 * w0.x; acc[0][1] += a0 * w0.y; acc[0][2]  += a0 * w0.z; acc[0][3]  += a0 * w0.w;
            acc[0][4] += a0 * w1.x; acc[0][5] += a0 * w1.y; acc[0][6]  += a0 * w1.z; acc[0][7]  += a0 * w1.w;
            acc[0][8] += a0 * w2.x; acc[0][9] += a0 * w2.y; acc[0][10] += a0 * w2.z; acc[0][11] += a0 * w2.w;
            acc[1][0] += a1 * w0.x; acc[1][1] += a1 * w0.y; acc[1][2]  += a1 * w0.z; acc[1][3]  += a1 * w0.w;
            acc[1][4] += a1 * w1.x; acc[1][5] += a1 * w1.y; acc[1][6]  += a1 * w1.z; acc[1][7]  += a1 * w1.w;
            acc[1][8] += a1 * w2.x; acc[1][9] += a1 * w2.y; acc[1][10] += a1 * w2.z; acc[1][11] += a1 * w2.w;
        }
        __syncthreads();
    }

    float as_h[12], ad_h[12];
#pragma unroll
    for (int j = 0; j < 12; j++) { as_h[j] = asrc[cg * 12 + j]; ad_h[j] = adst[cg * 12 + j]; }

#pragma unroll
    for (int i = 0; i < 2; i++) {
        int gr = n0 + r + 32 * i;
        if (gr < M) {
            float s_ = 0.f, d_ = 0.f;
#pragma unroll
            for (int j = 0; j < 12; j++) {
                s_ += acc[i][j] * as_h[j];
                d_ += acc[i][j] * ad_h[j];
            }
            __half2* op = (__half2*)(Hout + (size_t)gr * D_HID + cg * 12);
#pragma unroll
            for (int j = 0; j < 6; j++)
                op[j] = __floats2half2_rn(acc[i][2 * j], acc[i][2 * j + 1]);
            aS[gr * NHEAD + cg] = s_;
            aD[gr * NHEAD + cg] = d_;
        }
    }
}

// ---------------- GAT aggregation: thread per (node, head), single pass ----------------
__device__ __forceinline__ void agg_edge(const __half* __restrict__ h, int s, int hh,
                                         float p, float* acc) {
    const uint2* hp = (const uint2*)(h + (size_t)s * D_HID + hh * 12);
    uint2 q0 = hp[0], q1 = hp[1], q2 = hp[2];
    float2 f0 = __half22float2(((const __half2*)&q0)[0]);
    float2 f1 = __half22float2(((const __half2*)&q0)[1]);
    float2 f2 = __half22float2(((const __half2*)&q1)[0]);
    float2 f3 = __half22float2(((const __half2*)&q1)[1]);
    float2 f4 = __half22float2(((const __half2*)&q2)[0]);
    float2 f5 = __half22float2(((const __half2*)&q2)[1]);
    acc[0] += p * f0.x; acc[1]  += p * f0.y;
    acc[2] += p * f1.x; acc[3]  += p * f1.y;
    acc[4] += p * f2.x; acc[5]  += p * f2.y;
    acc[6] += p * f3.x; acc[7]  += p * f3.y;
    acc[8] += p * f4.x; acc[9]  += p * f4.y;
    acc[10] += p * f5.x; acc[11] += p * f5.y;
}

__global__ __launch_bounds__(256) void gat_aggregate_kernel(
    const __half* __restrict__ h, const float* __restrict__ aS, const float* __restrict__ aD,
    const int* __restrict__ rowptr, const unsigned short* __restrict__ srclist,
    const float* __restrict__ bias, float* __restrict__ out, int relu)
{
    int gid = blockIdx.x * blockDim.x + threadIdx.x;
    if (gid >= N_NODES * NHEAD) return;
    int n  = gid >> 3;
    int hh = gid & 7;
    int s0 = rowptr[n], s1 = rowptr[n + 1];
    float ad = aD[n * NHEAD + hh];

    float z = 0.f;
    float acc[12];
#pragma unroll
    for (int j = 0; j < 12; j++) acc[j] = 0.f;

    int i = s0;
    for (; i + 4 <= s1; i += 4) {
        int sa = srclist[i];
        int sb = srclist[i + 1];
        int sc = srclist[i + 2];
        int sd = srclist[i + 3];
        float ea = aS[sa * NHEAD + hh] + ad;
        float eb = aS[sb * NHEAD + hh] + ad;
        float ec = aS[sc * NHEAD + hh] + ad;
        float ed = aS[sd * NHEAD + hh] + ad;
        ea = (ea > 0.f) ? ea : NEG_SLOPE * ea;
        eb = (eb > 0.f) ? eb : NEG_SLOPE * eb;
        ec = (ec > 0.f) ? ec : NEG_SLOPE * ec;
        ed = (ed > 0.f) ? ed : NEG_SLOPE * ed;
        float pa = __expf(ea);
        float pb = __expf(eb);
        float pc = __expf(ec);
        float pd = __expf(ed);
        z += (pa + pb) + (pc + pd);
        agg_edge(h, sa, hh, pa, acc);
        agg_edge(h, sb, hh, pb, acc);
        agg_edge(h, sc, hh, pc, acc);
        agg_edge(h, sd, hh, pd, acc);
    }
    for (; i < s1; i++) {
        int sa = srclist[i];
        float ea = aS[sa * NHEAD + hh] + ad;
        ea = (ea > 0.f) ? ea : NEG_SLOPE * ea;
        float pa = __expf(ea);
        z += pa;
        agg_edge(h, sa, hh, pa, acc);
    }

    float inv = 1.f / (z + 1e-16f);
    const float* bp = bias + hh * 12;
    float o[12];
#pragma unroll
    for (int j = 0; j < 12; j++) o[j] = acc[j] * inv + bp[j];
    if (relu) {
#pragma unroll
        for (int j = 0; j < 12; j++) o[j] = fmaxf(o[j], 0.f);
    }
    float4* op = (float4*)(out + (size_t)n * D_HID + hh * 12);
    op[0] = make_float4(o[0], o[1], o[2], o[3]);
    op[1] = make_float4(o[4], o[5], o[6], o[7]);
    op[2] = make_float4(o[8], o[9], o[10], o[11]);
}

// ---------------- final linear (96->40) + bias + log_softmax, thread per node ----------------
__global__ __launch_bounds__(256) void out_lsm_kernel(
    const float* __restrict__ X, const float* __restrict__ Wout,
    const float* __restrict__ bout, float* __restrict__ out)
{
    __shared__ float Ws[D_HID * N_CLS];
    __shared__ float bs[N_CLS];
    for (int i = threadIdx.x; i < D_HID * N_CLS; i += 256) Ws[i] = Wout[i];
    for (int i = threadIdx.x; i < N_CLS; i += 256) bs[i] = bout[i];
    __syncthreads();

    int n = blockIdx.x * blockDim.x + threadIdx.x;
    if (n >= N_NODES) return;

    float acc[N_CLS];
#pragma unroll
    for (int c = 0; c < N_CLS; c++) acc[c] = bs[c];

    const float4* xp = (const float4*)(X + (size_t)n * D_HID);
    for (int k4 = 0; k4 < D_HID / 4; k4++) {
        float4 xv = xp[k4];
        const float* wrow = &Ws[(k4 * 4) * N_CLS];
#pragma unroll
        for (int c4 = 0; c4 < N_CLS / 4; c4++) {
            float4 wa = *(const float4*)(wrow + c4 * 4);
            float4 wb = *(const float4*)(wrow + N_CLS + c4 * 4);
            float4 wc = *(const float4*)(wrow + 2 * N_CLS + c4 * 4);
            float4 wd = *(const float4*)(wrow + 3 * N_CLS + c4 * 4);
            acc[c4 * 4 + 0] += xv.x * wa.x + xv.y * wb.x + xv.z * wc.x + xv.w * wd.x;
            acc[c4 * 4 + 1] += xv.x * wa.y + xv.y * wb.y + xv.z * wc.y + xv.w * wd.y;
            acc[c4 * 4 + 2] += xv.x * wa.z + xv.y * wb.z + xv.z * wc.z + xv.w * wd.z;
            acc[c4 * 4 + 3] += xv.x * wa.w + xv.y * wb.w + xv.z * wc.w + xv.w * wd.w;
        }
    }

    float m = acc[0];
#pragma unroll
    for (int c = 1; c < N_CLS; c++) m = fmaxf(m, acc[c]);
    float s = 0.f;
#pragma unroll
    for (int c = 0; c < N_CLS; c++) s += __expf(acc[c] - m);
    float lg = __logf(s);

    float4* op = (float4*)(out + (size_t)n * N_CLS);
#pragma unroll
    for (int c4 = 0; c4 < N_CLS / 4; c4++) {
        op[c4] = make_float4(acc[c4 * 4 + 0] - m - lg, acc[c4 * 4 + 1] - m - lg,
                             acc[c4 * 4 + 2] - m - lg, acc[c4 * 4 + 3] - m - lg);
    }
}

extern "C" void kernel_launch(void* const* d_in, const int* in_sizes, int n_in,
                              void* d_out, int out_size, void* d_ws, size_t ws_size,
                              hipStream_t stream)
{
    const float* x    = (const float*)d_in[0];
    const int*   esrc = (const int*)d_in[1];
    const int*   edst = (const int*)d_in[2];
    const float* W0   = (const float*)d_in[3];
    const float* as0  = (const float*)d_in[4];
    const float* ad0  = (const float*)d_in[5];
    const float* b0   = (const float*)d_in[6];
    const float* W1   = (const float*)d_in[7];
    const float* as1  = (const float*)d_in[8];
    const float* ad1  = (const float*)d_in[9];
    const float* b1   = (const float*)d_in[10];
    const float* Wout = (const float*)d_in[11];
    const float* bout = (const float*)d_in[12];
    float* out = (float*)d_out;

    char* p = (char*)d_ws;
    float* bufY   = (float*)p; p += (size_t)N_NODES * D_HID * sizeof(float);
    float* aS     = (float*)p; p += (size_t)N_NODES * NHEAD * sizeof(float);
    float* aD     = (float*)p; p += (size_t)N_NODES * NHEAD * sizeof(float);
    __half* bufH  = (__half*)p; p += (size_t)N_NODES * D_HID * sizeof(__half);
    int*   cnt    = (int*)p;   p += ((size_t)N_NODES + 16) * sizeof(int);
    int*   rowptr = (int*)p;   p += ((size_t)N_NODES + 16) * sizeof(int);
    int*   cursor = (int*)p;   p += ((size_t)N_NODES + 16) * sizeof(int);
    unsigned short* srclist = (unsigned short*)p; p += (size_t)N_EDGES * sizeof(unsigned short);
    int*   partials=(int*)p;   p += 256;

    // CSR build (by dst), XCD-partitioned
    hipMemsetAsync(cnt, 0, N_NODES * sizeof(int), stream);
    hist_part_kernel<<<256, 256, 0, stream>>>(edst, cnt);
    int nscan = (N_NODES + 1023) / 1024;
    scan1_kernel<<<nscan, 256, 0, stream>>>(cnt, cursor, partials, N_NODES);
    scan2_kernel<<<1, 64, 0, stream>>>(partials, nscan);
    scan3_kernel<<<(N_NODES + 255) / 256, 256, 0, stream>>>(cnt, cursor, partials, rowptr, N_NODES);
    fill_part_kernel<<<256, 256, 0, stream>>>(esrc, edst, cursor, srclist);

    // layer 0: h0 = x @ W0, alphas; aggregate + b0 (no relu)
    gemm_alpha_kernel<<<(N_NODES + BM - 1) / BM, 256, 0, stream>>>(
        x, W0, as0, ad0, bufH, aS, aD, N_NODES, F_IN);
    gat_aggregate_kernel<<<(N_NODES * NHEAD + 255) / 256, 256, 0, stream>>>(
        bufH, aS, aD, rowptr, srclist, b0, bufY, 0);

    // layer 1: h1 = y0 @ W1, alphas; aggregate + b1 + relu
    gemm_alpha_kernel<<<(N_NODES + BM - 1) / BM, 256, 0, stream>>>(
        bufY, W1, as1, ad1, bufH, aS, aD, N_NODES, D_HID);
    gat_aggregate_kernel<<<(N_NODES * NHEAD + 255) / 256, 256, 0, stream>>>(
        bufH, aS, aD, rowptr, srclist, b1, bufY, 1);

    // output linear + log_softmax
    out_lsm_kernel<<<(N_NODES + 255) / 256, 256, 0, stream>>>(bufY, Wout, bout, out);
}

// Round 4
// 257.200 us; speedup vs baseline: 1.1746x; 1.1746x over previous
//
#include <hip/hip_runtime.h>
#include <hip/hip_fp16.h>
#include <math.h>

#define N_NODES 50000
#define N_EDGES 800000
#define F_IN    128
#define D_HID   96
#define NHEAD   8
#define DH      12
#define N_CLS   40
#define NEG_SLOPE 0.2f

#define NPART   (N_NODES / 8)        // 6250 dst nodes per XCD group
#define NWCHUNK 256                  // edge chunks per group
#define ECHUNK  (N_EDGES / NWCHUNK)  // 3125 edges per chunk

// ---------------- CSR build (XCD-partitioned by dst range) ----------------
// 2048 blocks: group g = blockIdx&7 owns dst in [g*NPART,(g+1)*NPART) and (by
// round-robin dispatch) runs on XCD g; block w = blockIdx>>3 scans edge chunk
// [w*ECHUNK,(w+1)*ECHUNK). All cnt/cursor atomics and srclist lines are
// single-XCD-owned -> stay in that XCD's L2.
__global__ __launch_bounds__(256) void hist_part_kernel(
    const int* __restrict__ edst, int* __restrict__ cnt)
{
    int lo = (blockIdx.x & 7) * NPART;
    int e0 = (blockIdx.x >> 3) * ECHUNK;
    for (int e = e0 + threadIdx.x; e < e0 + ECHUNK; e += 256) {
        int d = edst[e] - lo;
        if ((unsigned)d < (unsigned)NPART) atomicAdd(&cnt[lo + d], 1);
    }
}

__global__ void scan1_kernel(const int* __restrict__ cnt, int* __restrict__ incl,
                             int* __restrict__ partials, int n) {
    __shared__ int sdata[256];
    int t = threadIdx.x;
    int base = blockIdx.x * 1024 + t * 4;
    int v[4];
#pragma unroll
    for (int j = 0; j < 4; j++) { int i = base + j; v[j] = (i < n) ? cnt[i] : 0; }
    v[1] += v[0]; v[2] += v[1]; v[3] += v[2];
    sdata[t] = v[3];
    __syncthreads();
    for (int off = 1; off < 256; off <<= 1) {
        int x = (t >= off) ? sdata[t - off] : 0;
        __syncthreads();
        sdata[t] += x;
        __syncthreads();
    }
    int excl = sdata[t] - v[3];
#pragma unroll
    for (int j = 0; j < 4; j++) { int i = base + j; if (i < n) incl[i] = v[j] + excl; }
    if (t == 255) partials[blockIdx.x] = sdata[255];
}

__global__ void scan2_kernel(int* partials, int nb) {
    if (threadIdx.x == 0 && blockIdx.x == 0) {
        int run = 0;
        for (int i = 0; i < nb; i++) { int v = partials[i]; partials[i] = run; run += v; }
    }
}

__global__ void scan3_kernel(const int* __restrict__ cnt, int* __restrict__ incl_cursor,
                             const int* __restrict__ partials, int* __restrict__ rowptr, int n) {
    int i = blockIdx.x * blockDim.x + threadIdx.x;
    if (i >= n) return;
    int v = incl_cursor[i] + partials[i >> 10];
    rowptr[i + 1] = v;
    incl_cursor[i] = v - cnt[i];
    if (i == 0) rowptr[0] = 0;
}

__global__ __launch_bounds__(256) void fill_part_kernel(
    const int* __restrict__ esrc, const int* __restrict__ edst,
    int* __restrict__ cursor, unsigned short* __restrict__ srclist)
{
    int lo = (blockIdx.x & 7) * NPART;
    int e0 = (blockIdx.x >> 3) * ECHUNK;
    for (int e = e0 + threadIdx.x; e < e0 + ECHUNK; e += 256) {
        int d = edst[e] - lo;
        if ((unsigned)d < (unsigned)NPART) {
            int p = atomicAdd(&cursor[lo + d], 1);
            srclist[p] = (unsigned short)esrc[e];
        }
    }
}

// ---------------- GEMM (A[M,K] @ W[K,96]) + per-head alpha epilogue ----------------
#define BM 64
#define BK 32
__global__ __launch_bounds__(256) void gemm_alpha_kernel(
    const float* __restrict__ A, const float* __restrict__ W,
    const float* __restrict__ asrc, const float* __restrict__ adst,
    __half* __restrict__ Hout, float* __restrict__ aS, float* __restrict__ aD,
    int M, int K)
{
    __shared__ float As[BM][BK + 1];
    __shared__ float Ws[BK][D_HID];
    int tid = threadIdx.x;
    int r   = tid & 31;
    int cg  = tid >> 5;           // head index 0..7
    int n0  = blockIdx.x * BM;

    float acc[2][12];
#pragma unroll
    for (int i = 0; i < 2; i++)
#pragma unroll
        for (int j = 0; j < 12; j++) acc[i][j] = 0.f;

    int wrow = tid >> 3;
    int wcol = (tid & 7) * 12;

    for (int k0 = 0; k0 < K; k0 += BK) {
        for (int idx = tid; idx < BM * BK; idx += 256) {
            int row = idx >> 5, col = idx & 31;
            int gr = n0 + row;
            As[row][col] = (gr < M) ? A[(size_t)gr * K + k0 + col] : 0.f;
        }
        {
            const float* wp = W + (size_t)(k0 + wrow) * D_HID + wcol;
#pragma unroll
            for (int j = 0; j < 12; j++) Ws[wrow][wcol + j] = wp[j];
        }
        __syncthreads();
#pragma unroll 8
        for (int kk = 0; kk < BK; kk++) {
            float4 w0 = *(const float4*)&Ws[kk][cg * 12];
            float4 w1 = *(const float4*)&Ws[kk][cg * 12 + 4];
            float4 w2 = *(const float4*)&Ws[kk][cg * 12 + 8];
            float a0 = As[r][kk];
            float a1 = As[r + 32][kk];
            acc[0][0] += a0 * w0.x; acc[0][1] += a0 * w0.y; acc[0][2]  += a0 * w0.z; acc[0][3]  += a0 * w0.w;
            acc[0][4] += a0 * w1.x; acc[0][5] += a0 * w1.y; acc[0][6]  += a0 * w1.z; acc[0][7]  += a0 * w1.w;
            acc[0][8] += a0 * w2.x; acc[0][9] += a0 * w2.y; acc[0][10] += a0 * w2.z; acc[0][11] += a0 * w2.w;
            acc[1][0] += a1 * w0.x; acc[1][1] += a1 * w0.y; acc[1][2]  += a1 * w0.z; acc[1][3]  += a1 * w0.w;
            acc[1][4] += a1 * w1.x; acc[1][5] += a1 * w1.y; acc[1][6]  += a1 * w1.z; acc[1][7]  += a1 * w1.w;
            acc[1][8] += a1 * w2.x; acc[1][9] += a1 * w2.y; acc[1][10] += a1 * w2.z; acc[1][11] += a1 * w2.w;
        }
        __syncthreads();
    }

    float as_h[12], ad_h[12];
#pragma unroll
    for (int j = 0; j < 12; j++) { as_h[j] = asrc[cg * 12 + j]; ad_h[j] = adst[cg * 12 + j]; }

#pragma unroll
    for (int i = 0; i < 2; i++) {
        int gr = n0 + r + 32 * i;
        if (gr < M) {
            float s_ = 0.f, d_ = 0.f;
#pragma unroll
            for (int j = 0; j < 12; j++) {
                s_ += acc[i][j] * as_h[j];
                d_ += acc[i][j] * ad_h[j];
            }
            __half2* op = (__half2*)(Hout + (size_t)gr * D_HID + cg * 12);
#pragma unroll
            for (int j = 0; j < 6; j++)
                op[j] = __floats2half2_rn(acc[i][2 * j], acc[i][2 * j + 1]);
            aS[gr * NHEAD + cg] = s_;
            aD[gr * NHEAD + cg] = d_;
        }
    }
}

// ---------------- GAT aggregation: thread per (node, head), single pass ----------------
__device__ __forceinline__ void agg_edge(const __half* __restrict__ h, int s, int hh,
                                         float p, float* acc) {
    const uint2* hp = (const uint2*)(h + (size_t)s * D_HID + hh * 12);
    uint2 q0 = hp[0], q1 = hp[1], q2 = hp[2];
    float2 f0 = __half22float2(((const __half2*)&q0)[0]);
    float2 f1 = __half22float2(((const __half2*)&q0)[1]);
    float2 f2 = __half22float2(((const __half2*)&q1)[0]);
    float2 f3 = __half22float2(((const __half2*)&q1)[1]);
    float2 f4 = __half22float2(((const __half2*)&q2)[0]);
    float2 f5 = __half22float2(((const __half2*)&q2)[1]);
    acc[0] += p * f0.x; acc[1]  += p * f0.y;
    acc[2] += p * f1.x; acc[3]  += p * f1.y;
    acc[4] += p * f2.x; acc[5]  += p * f2.y;
    acc[6] += p * f3.x; acc[7]  += p * f3.y;
    acc[8] += p * f4.x; acc[9]  += p * f4.y;
    acc[10] += p * f5.x; acc[11] += p * f5.y;
}

__global__ __launch_bounds__(256) void gat_aggregate_kernel(
    const __half* __restrict__ h, const float* __restrict__ aS, const float* __restrict__ aD,
    const int* __restrict__ rowptr, const unsigned short* __restrict__ srclist,
    const float* __restrict__ bias, float* __restrict__ out, int relu)
{
    int gid = blockIdx.x * blockDim.x + threadIdx.x;
    if (gid >= N_NODES * NHEAD) return;
    int n  = gid >> 3;
    int hh = gid & 7;
    int s0 = rowptr[n], s1 = rowptr[n + 1];
    float ad = aD[n * NHEAD + hh];

    float z = 0.f;
    float acc[12];
#pragma unroll
    for (int j = 0; j < 12; j++) acc[j] = 0.f;

    int i = s0;
    for (; i + 4 <= s1; i += 4) {
        int sa = srclist[i];
        int sb = srclist[i + 1];
        int sc = srclist[i + 2];
        int sd = srclist[i + 3];
        float ea = aS[sa * NHEAD + hh] + ad;
        float eb = aS[sb * NHEAD + hh] + ad;
        float ec = aS[sc * NHEAD + hh] + ad;
        float ed = aS[sd * NHEAD + hh] + ad;
        ea = (ea > 0.f) ? ea : NEG_SLOPE * ea;
        eb = (eb > 0.f) ? eb : NEG_SLOPE * eb;
        ec = (ec > 0.f) ? ec : NEG_SLOPE * ec;
        ed = (ed > 0.f) ? ed : NEG_SLOPE * ed;
        float pa = __expf(ea);
        float pb = __expf(eb);
        float pc = __expf(ec);
        float pd = __expf(ed);
        z += (pa + pb) + (pc + pd);
        agg_edge(h, sa, hh, pa, acc);
        agg_edge(h, sb, hh, pb, acc);
        agg_edge(h, sc, hh, pc, acc);
        agg_edge(h, sd, hh, pd, acc);
    }
    for (; i < s1; i++) {
        int sa = srclist[i];
        float ea = aS[sa * NHEAD + hh] + ad;
        ea = (ea > 0.f) ? ea : NEG_SLOPE * ea;
        float pa = __expf(ea);
        z += pa;
        agg_edge(h, sa, hh, pa, acc);
    }

    float inv = 1.f / (z + 1e-16f);
    const float* bp = bias + hh * 12;
    float o[12];
#pragma unroll
    for (int j = 0; j < 12; j++) o[j] = acc[j] * inv + bp[j];
    if (relu) {
#pragma unroll
        for (int j = 0; j < 12; j++) o[j] = fmaxf(o[j], 0.f);
    }
    float4* op = (float4*)(out + (size_t)n * D_HID + hh * 12);
    op[0] = make_float4(o[0], o[1], o[2], o[3]);
    op[1] = make_float4(o[4], o[5], o[6], o[7]);
    op[2] = make_float4(o[8], o[9], o[10], o[11]);
}

// ---------------- final linear (96->40) + bias + log_softmax, thread per node ----------------
__global__ __launch_bounds__(256) void out_lsm_kernel(
    const float* __restrict__ X, const float* __restrict__ Wout,
    const float* __restrict__ bout, float* __restrict__ out)
{
    __shared__ float Ws[D_HID * N_CLS];
    __shared__ float bs[N_CLS];
    for (int i = threadIdx.x; i < D_HID * N_CLS; i += 256) Ws[i] = Wout[i];
    for (int i = threadIdx.x; i < N_CLS; i += 256) bs[i] = bout[i];
    __syncthreads();

    int n = blockIdx.x * blockDim.x + threadIdx.x;
    if (n >= N_NODES) return;

    float acc[N_CLS];
#pragma unroll
    for (int c = 0; c < N_CLS; c++) acc[c] = bs[c];

    const float4* xp = (const float4*)(X + (size_t)n * D_HID);
    for (int k4 = 0; k4 < D_HID / 4; k4++) {
        float4 xv = xp[k4];
        const float* wrow = &Ws[(k4 * 4) * N_CLS];
#pragma unroll
        for (int c4 = 0; c4 < N_CLS / 4; c4++) {
            float4 wa = *(const float4*)(wrow + c4 * 4);
            float4 wb = *(const float4*)(wrow + N_CLS + c4 * 4);
            float4 wc = *(const float4*)(wrow + 2 * N_CLS + c4 * 4);
            float4 wd = *(const float4*)(wrow + 3 * N_CLS + c4 * 4);
            acc[c4 * 4 + 0] += xv.x * wa.x + xv.y * wb.x + xv.z * wc.x + xv.w * wd.x;
            acc[c4 * 4 + 1] += xv.x * wa.y + xv.y * wb.y + xv.z * wc.y + xv.w * wd.y;
            acc[c4 * 4 + 2] += xv.x * wa.z + xv.y * wb.z + xv.z * wc.z + xv.w * wd.z;
            acc[c4 * 4 + 3] += xv.x * wa.w + xv.y * wb.w + xv.z * wc.w + xv.w * wd.w;
        }
    }

    float m = acc[0];
#pragma unroll
    for (int c = 1; c < N_CLS; c++) m = fmaxf(m, acc[c]);
    float s = 0.f;
#pragma unroll
    for (int c = 0; c < N_CLS; c++) s += __expf(acc[c] - m);
    float lg = __logf(s);

    float4* op = (float4*)(out + (size_t)n * N_CLS);
#pragma unroll
    for (int c4 = 0; c4 < N_CLS / 4; c4++) {
        op[c4] = make_float4(acc[c4 * 4 + 0] - m - lg, acc[c4 * 4 + 1] - m - lg,
                             acc[c4 * 4 + 2] - m - lg, acc[c4 * 4 + 3] - m - lg);
    }
}

extern "C" void kernel_launch(void* const* d_in, const int* in_sizes, int n_in,
                              void* d_out, int out_size, void* d_ws, size_t ws_size,
                              hipStream_t stream)
{
    const float* x    = (const float*)d_in[0];
    const int*   esrc = (const int*)d_in[1];
    const int*   edst = (const int*)d_in[2];
    const float* W0   = (const float*)d_in[3];
    const float* as0  = (const float*)d_in[4];
    const float* ad0  = (const float*)d_in[5];
    const float* b0   = (const float*)d_in[6];
    const float* W1   = (const float*)d_in[7];
    const float* as1  = (const float*)d_in[8];
    const float* ad1  = (const float*)d_in[9];
    const float* b1   = (const float*)d_in[10];
    const float* Wout = (const float*)d_in[11];
    const float* bout = (const float*)d_in[12];
    float* out = (float*)d_out;

    char* p = (char*)d_ws;
    float* bufY   = (float*)p; p += (size_t)N_NODES * D_HID * sizeof(float);
    float* aS     = (float*)p; p += (size_t)N_NODES * NHEAD * sizeof(float);
    float* aD     = (float*)p; p += (size_t)N_NODES * NHEAD * sizeof(float);
    __half* bufH  = (__half*)p; p += (size_t)N_NODES * D_HID * sizeof(__half);
    int*   cnt    = (int*)p;   p += ((size_t)N_NODES + 16) * sizeof(int);
    int*   rowptr = (int*)p;   p += ((size_t)N_NODES + 16) * sizeof(int);
    int*   cursor = (int*)p;   p += ((size_t)N_NODES + 16) * sizeof(int);
    unsigned short* srclist = (unsigned short*)p; p += (size_t)N_EDGES * sizeof(unsigned short);
    int*   partials=(int*)p;   p += 256;

    // CSR build (by dst), XCD-partitioned, 2048 blocks for occupancy
    hipMemsetAsync(cnt, 0, N_NODES * sizeof(int), stream);
    hist_part_kernel<<<8 * NWCHUNK, 256, 0, stream>>>(edst, cnt);
    int nscan = (N_NODES + 1023) / 1024;
    scan1_kernel<<<nscan, 256, 0, stream>>>(cnt, cursor, partials, N_NODES);
    scan2_kernel<<<1, 64, 0, stream>>>(partials, nscan);
    scan3_kernel<<<(N_NODES + 255) / 256, 256, 0, stream>>>(cnt, cursor, partials, rowptr, N_NODES);
    fill_part_kernel<<<8 * NWCHUNK, 256, 0, stream>>>(esrc, edst, cursor, srclist);

    // layer 0: h0 = x @ W0, alphas; aggregate + b0 (no relu)
    gemm_alpha_kernel<<<(N_NODES + BM - 1) / BM, 256, 0, stream>>>(
        x, W0, as0, ad0, bufH, aS, aD, N_NODES, F_IN);
    gat_aggregate_kernel<<<(N_NODES * NHEAD + 255) / 256, 256, 0, stream>>>(
        bufH, aS, aD, rowptr, srclist, b0, bufY, 0);

    // layer 1: h1 = y0 @ W1, alphas; aggregate + b1 + relu
    gemm_alpha_kernel<<<(N_NODES + BM - 1) / BM, 256, 0, stream>>>(
        bufY, W1, as1, ad1, bufH, aS, aD, N_NODES, D_HID);
    gat_aggregate_kernel<<<(N_NODES * NHEAD + 255) / 256, 256, 0, stream>>>(
        bufH, aS, aD, rowptr, srclist, b1, bufY, 1);

    // output linear + log_softmax
    out_lsm_kernel<<<(N_NODES + 255) / 256, 256, 0, stream>>>(bufY, Wout, bout, out);
}

// Round 5
// 244.961 us; speedup vs baseline: 1.2333x; 1.0500x over previous
//
#include <hip/hip_runtime.h>
#include <hip/hip_fp16.h>
#include <math.h>

#define N_NODES 50000
#define N_EDGES 800000
#define F_IN    128
#define D_HID   96
#define NHEAD   8
#define DH      12
#define N_CLS   40
#define NEG_SLOPE 0.2f

#define NPART   (N_NODES / 8)        // 6250 dst nodes per XCD group
#define NWCHUNK 256                  // edge chunks per group
#define ECHUNK  (N_EDGES / NWCHUNK)  // 3125 edges per chunk
#define NHISTB  (8 * NWCHUNK)        // 2048 hist/fill blocks

#define BM 64
#define BK 32
#define NGEMM0  ((N_NODES + BM - 1) / BM)   // 782

// ---------------- zero cnt (custom: runtime fillBuffer is ~40us for 200KB) ----------------
__global__ __launch_bounds__(256) void zero_kernel(int4* __restrict__ p, int n4) {
    int i = blockIdx.x * blockDim.x + threadIdx.x;
    if (i < n4) p[i] = make_int4(0, 0, 0, 0);
}

// ---------------- GEMM core (A[M,K] @ W[K,96]) + per-head alpha epilogue ----------------
__device__ __forceinline__ void gemm_alpha_body(
    const float* __restrict__ A, const float* __restrict__ W,
    const float* __restrict__ asrc, const float* __restrict__ adst,
    __half* __restrict__ Hout, float* __restrict__ aS, float* __restrict__ aD,
    int M, int K, int bid,
    float (*As)[BK + 1], float (*Ws)[D_HID])
{
    int tid = threadIdx.x;
    int r   = tid & 31;
    int cg  = tid >> 5;           // head index 0..7
    int n0  = bid * BM;

    float acc[2][12];
#pragma unroll
    for (int i = 0; i < 2; i++)
#pragma unroll
        for (int j = 0; j < 12; j++) acc[i][j] = 0.f;

    int wrow = tid >> 3;
    int wcol = (tid & 7) * 12;

    for (int k0 = 0; k0 < K; k0 += BK) {
        for (int idx = tid; idx < BM * BK; idx += 256) {
            int row = idx >> 5, col = idx & 31;
            int gr = n0 + row;
            As[row][col] = (gr < M) ? A[(size_t)gr * K + k0 + col] : 0.f;
        }
        {
            const float* wp = W + (size_t)(k0 + wrow) * D_HID + wcol;
#pragma unroll
            for (int j = 0; j < 12; j++) Ws[wrow][wcol + j] = wp[j];
        }
        __syncthreads();
#pragma unroll 8
        for (int kk = 0; kk < BK; kk++) {
            float4 w0 = *(const float4*)&Ws[kk][cg * 12];
            float4 w1 = *(const float4*)&Ws[kk][cg * 12 + 4];
            float4 w2 = *(const float4*)&Ws[kk][cg * 12 + 8];
            float a0 = As[r][kk];
            float a1 = As[r + 32][kk];
            acc[0][0] += a0 * w0.x; acc[0][1] += a0 * w0.y; acc[0][2]  += a0 * w0.z; acc[0][3]  += a0 * w0.w;
            acc[0][4] += a0 * w1.x; acc[0][5] += a0 * w1.y; acc[0][6]  += a0 * w1.z; acc[0][7]  += a0 * w1.w;
            acc[0][8] += a0 * w2.x; acc[0][9] += a0 * w2.y; acc[0][10] += a0 * w2.z; acc[0][11] += a0 * w2.w;
            acc[1][0] += a1 * w0.x; acc[1][1] += a1 * w0.y; acc[1][2]  += a1 * w0.z; acc[1][3]  += a1 * w0.w;
            acc[1][4] += a1 * w1.x; acc[1][5] += a1 * w1.y; acc[1][6]  += a1 * w1.z; acc[1][7]  += a1 * w1.w;
            acc[1][8] += a1 * w2.x; acc[1][9] += a1 * w2.y; acc[1][10] += a1 * w2.z; acc[1][11] += a1 * w2.w;
        }
        __syncthreads();
    }

    float as_h[12], ad_h[12];
#pragma unroll
    for (int j = 0; j < 12; j++) { as_h[j] = asrc[cg * 12 + j]; ad_h[j] = adst[cg * 12 + j]; }

#pragma unroll
    for (int i = 0; i < 2; i++) {
        int gr = n0 + r + 32 * i;
        if (gr < M) {
            float s_ = 0.f, d_ = 0.f;
#pragma unroll
            for (int j = 0; j < 12; j++) {
                s_ += acc[i][j] * as_h[j];
                d_ += acc[i][j] * ad_h[j];
            }
            __half2* op = (__half2*)(Hout + (size_t)gr * D_HID + cg * 12);
#pragma unroll
            for (int j = 0; j < 6; j++)
                op[j] = __floats2half2_rn(acc[i][2 * j], acc[i][2 * j + 1]);
            aS[gr * NHEAD + cg] = s_;
            aD[gr * NHEAD + cg] = d_;
        }
    }
}

// ---------------- fused: hist (blocks [0,NHISTB)) + gemm0 (blocks [NHISTB,..)) ----------------
__global__ __launch_bounds__(256) void hist_gemm_kernel(
    const int* __restrict__ edst, int* __restrict__ cnt,
    const float* __restrict__ A, const float* __restrict__ W,
    const float* __restrict__ asrc, const float* __restrict__ adst,
    __half* __restrict__ Hout, float* __restrict__ aS, float* __restrict__ aD)
{
    __shared__ float As[BM][BK + 1];
    __shared__ float Ws[BK][D_HID];
    if (blockIdx.x < NHISTB) {
        int lo = (blockIdx.x & 7) * NPART;   // bid&7 == XCD (round-robin dispatch)
        int e0 = (blockIdx.x >> 3) * ECHUNK;
        for (int e = e0 + threadIdx.x; e < e0 + ECHUNK; e += 256) {
            int d = edst[e] - lo;
            if ((unsigned)d < (unsigned)NPART) atomicAdd(&cnt[lo + d], 1);
        }
    } else {
        gemm_alpha_body(A, W, asrc, adst, Hout, aS, aD, N_NODES, F_IN,
                        blockIdx.x - NHISTB, As, Ws);
    }
}

// ---------------- standalone gemm (layer 1) ----------------
__global__ __launch_bounds__(256) void gemm_alpha_kernel(
    const float* __restrict__ A, const float* __restrict__ W,
    const float* __restrict__ asrc, const float* __restrict__ adst,
    __half* __restrict__ Hout, float* __restrict__ aS, float* __restrict__ aD,
    int M, int K)
{
    __shared__ float As[BM][BK + 1];
    __shared__ float Ws[BK][D_HID];
    gemm_alpha_body(A, W, asrc, adst, Hout, aS, aD, M, K, blockIdx.x, As, Ws);
}

// ---------------- scans ----------------
__global__ void scan1_kernel(const int* __restrict__ cnt, int* __restrict__ incl,
                             int* __restrict__ partials, int n) {
    __shared__ int sdata[256];
    int t = threadIdx.x;
    int base = blockIdx.x * 1024 + t * 4;
    int v[4];
#pragma unroll
    for (int j = 0; j < 4; j++) { int i = base + j; v[j] = (i < n) ? cnt[i] : 0; }
    v[1] += v[0]; v[2] += v[1]; v[3] += v[2];
    sdata[t] = v[3];
    __syncthreads();
    for (int off = 1; off < 256; off <<= 1) {
        int x = (t >= off) ? sdata[t - off] : 0;
        __syncthreads();
        sdata[t] += x;
        __syncthreads();
    }
    int excl = sdata[t] - v[3];
#pragma unroll
    for (int j = 0; j < 4; j++) { int i = base + j; if (i < n) incl[i] = v[j] + excl; }
    if (t == 255) partials[blockIdx.x] = sdata[255];
}

// scan3 with inline prefix over raw partials (replaces scan2)
__global__ void scan3_kernel(const int* __restrict__ cnt, int* __restrict__ incl_cursor,
                             const int* __restrict__ partials, int* __restrict__ rowptr,
                             int n, int nb) {
    int i = blockIdx.x * blockDim.x + threadIdx.x;
    if (i >= n) return;
    int myb = i >> 10;
    int psum = 0;
    for (int b = 0; b < nb; b++) psum += (b < myb) ? partials[b] : 0;
    int v = incl_cursor[i] + psum;
    rowptr[i + 1] = v;
    incl_cursor[i] = v - cnt[i];
    if (i == 0) rowptr[0] = 0;
}

__global__ __launch_bounds__(256) void fill_part_kernel(
    const int* __restrict__ esrc, const int* __restrict__ edst,
    int* __restrict__ cursor, unsigned short* __restrict__ srclist)
{
    int lo = (blockIdx.x & 7) * NPART;
    int e0 = (blockIdx.x >> 3) * ECHUNK;
    for (int e = e0 + threadIdx.x; e < e0 + ECHUNK; e += 256) {
        int d = edst[e] - lo;
        if ((unsigned)d < (unsigned)NPART) {
            int p = atomicAdd(&cursor[lo + d], 1);
            srclist[p] = (unsigned short)esrc[e];
        }
    }
}

// ---------------- GAT aggregation core: thread per (node, head), single pass ----------------
__device__ __forceinline__ void agg_edge(const __half* __restrict__ h, int s, int hh,
                                         float p, float* acc) {
    const uint2* hp = (const uint2*)(h + (size_t)s * D_HID + hh * 12);
    uint2 q0 = hp[0], q1 = hp[1], q2 = hp[2];
    float2 f0 = __half22float2(((const __half2*)&q0)[0]);
    float2 f1 = __half22float2(((const __half2*)&q0)[1]);
    float2 f2 = __half22float2(((const __half2*)&q1)[0]);
    float2 f3 = __half22float2(((const __half2*)&q1)[1]);
    float2 f4 = __half22float2(((const __half2*)&q2)[0]);
    float2 f5 = __half22float2(((const __half2*)&q2)[1]);
    acc[0] += p * f0.x; acc[1]  += p * f0.y;
    acc[2] += p * f1.x; acc[3]  += p * f1.y;
    acc[4] += p * f2.x; acc[5]  += p * f2.y;
    acc[6] += p * f3.x; acc[7]  += p * f3.y;
    acc[8] += p * f4.x; acc[9]  += p * f4.y;
    acc[10] += p * f5.x; acc[11] += p * f5.y;
}

// computes o[12] = softmax-weighted sum + bias (optional relu) for (n, hh)
__device__ __forceinline__ void agg_body(
    const __half* __restrict__ h, const float* __restrict__ aS, const float* __restrict__ aD,
    const int* __restrict__ rowptr, const unsigned short* __restrict__ srclist,
    const float* __restrict__ bias, int n, int hh, int relu, float* o)
{
    int s0 = rowptr[n], s1 = rowptr[n + 1];
    float ad = aD[n * NHEAD + hh];

    float z = 0.f;
    float acc[12];
#pragma unroll
    for (int j = 0; j < 12; j++) acc[j] = 0.f;

    int i = s0;
    for (; i + 4 <= s1; i += 4) {
        int sa = srclist[i];
        int sb = srclist[i + 1];
        int sc = srclist[i + 2];
        int sd = srclist[i + 3];
        float ea = aS[sa * NHEAD + hh] + ad;
        float eb = aS[sb * NHEAD + hh] + ad;
        float ec = aS[sc * NHEAD + hh] + ad;
        float ed = aS[sd * NHEAD + hh] + ad;
        ea = (ea > 0.f) ? ea : NEG_SLOPE * ea;
        eb = (eb > 0.f) ? eb : NEG_SLOPE * eb;
        ec = (ec > 0.f) ? ec : NEG_SLOPE * ec;
        ed = (ed > 0.f) ? ed : NEG_SLOPE * ed;
        float pa = __expf(ea);
        float pb = __expf(eb);
        float pc = __expf(ec);
        float pd = __expf(ed);
        z += (pa + pb) + (pc + pd);
        agg_edge(h, sa, hh, pa, acc);
        agg_edge(h, sb, hh, pb, acc);
        agg_edge(h, sc, hh, pc, acc);
        agg_edge(h, sd, hh, pd, acc);
    }
    for (; i < s1; i++) {
        int sa = srclist[i];
        float ea = aS[sa * NHEAD + hh] + ad;
        ea = (ea > 0.f) ? ea : NEG_SLOPE * ea;
        float pa = __expf(ea);
        z += pa;
        agg_edge(h, sa, hh, pa, acc);
    }

    float inv = 1.f / (z + 1e-16f);
    const float* bp = bias + hh * 12;
#pragma unroll
    for (int j = 0; j < 12; j++) o[j] = acc[j] * inv + bp[j];
    if (relu) {
#pragma unroll
        for (int j = 0; j < 12; j++) o[j] = fmaxf(o[j], 0.f);
    }
}

// layer-0 aggregate: write bufY
__global__ __launch_bounds__(256) void gat_aggregate_kernel(
    const __half* __restrict__ h, const float* __restrict__ aS, const float* __restrict__ aD,
    const int* __restrict__ rowptr, const unsigned short* __restrict__ srclist,
    const float* __restrict__ bias, float* __restrict__ out)
{
    int gid = blockIdx.x * blockDim.x + threadIdx.x;
    if (gid >= N_NODES * NHEAD) return;
    int n  = gid >> 3;
    int hh = gid & 7;
    float o[12];
    agg_body(h, aS, aD, rowptr, srclist, bias, n, hh, 0, o);
    float4* op = (float4*)(out + (size_t)n * D_HID + hh * 12);
    op[0] = make_float4(o[0], o[1], o[2], o[3]);
    op[1] = make_float4(o[4], o[5], o[6], o[7]);
    op[2] = make_float4(o[8], o[9], o[10], o[11]);
}

// layer-1 aggregate + relu + (y @ Wout + bout) + log_softmax fused.
// The 8 heads of a node are 8 consecutive lanes of one wave (400000 % 64 == 0,
// so groups never straddle waves). Lane hh holds y[hh*12..hh*12+11]; partial
// products are butterfly-reduced over the 8 lanes via __shfl_xor.
__global__ __launch_bounds__(256) void gat_aggregate_final_kernel(
    const __half* __restrict__ h, const float* __restrict__ aS, const float* __restrict__ aD,
    const int* __restrict__ rowptr, const unsigned short* __restrict__ srclist,
    const float* __restrict__ bias,
    const float* __restrict__ Wout, const float* __restrict__ bout,
    float* __restrict__ out)
{
    __shared__ float Ws[D_HID][N_CLS + 1];   // pad to 41: rows hit distinct banks
    __shared__ float bs[N_CLS];
    for (int idx = threadIdx.x; idx < D_HID * N_CLS; idx += 256)
        Ws[idx / N_CLS][idx % N_CLS] = Wout[idx];
    for (int idx = threadIdx.x; idx < N_CLS; idx += 256) bs[idx] = bout[idx];
    __syncthreads();

    int gid = blockIdx.x * blockDim.x + threadIdx.x;
    if (gid >= N_NODES * NHEAD) return;
    int n  = gid >> 3;
    int hh = gid & 7;
    float o[12];
    agg_body(h, aS, aD, rowptr, srclist, bias, n, hh, 1, o);

    // partial[c] = sum over this lane's 12 rows of Wout
    float part[N_CLS];
#pragma unroll
    for (int c = 0; c < N_CLS; c++) part[c] = 0.f;
#pragma unroll
    for (int j = 0; j < 12; j++) {
        float oj = o[j];
        const float* wr = &Ws[hh * 12 + j][0];
#pragma unroll
        for (int c = 0; c < N_CLS; c++) part[c] += oj * wr[c];
    }
    // butterfly-reduce over the 8 head-lanes
#pragma unroll
    for (int d = 1; d < 8; d <<= 1) {
#pragma unroll
        for (int c = 0; c < N_CLS; c++) part[c] += __shfl_xor(part[c], d, 64);
    }
#pragma unroll
    for (int c = 0; c < N_CLS; c++) part[c] += bs[c];

    // log-softmax (all 8 lanes hold identical totals)
    float m = part[0];
#pragma unroll
    for (int c = 1; c < N_CLS; c++) m = fmaxf(m, part[c]);
    float sp = 0.f;
#pragma unroll
    for (int k = 0; k < 5; k++) sp += __expf(part[hh * 5 + k] - m);
#pragma unroll
    for (int d = 1; d < 8; d <<= 1) sp += __shfl_xor(sp, d, 64);
    float lg = __logf(sp);

    float* op = out + (size_t)n * N_CLS + hh * 5;
#pragma unroll
    for (int k = 0; k < 5; k++) op[k] = part[hh * 5 + k] - m - lg;
}

extern "C" void kernel_launch(void* const* d_in, const int* in_sizes, int n_in,
                              void* d_out, int out_size, void* d_ws, size_t ws_size,
                              hipStream_t stream)
{
    const float* x    = (const float*)d_in[0];
    const int*   esrc = (const int*)d_in[1];
    const int*   edst = (const int*)d_in[2];
    const float* W0   = (const float*)d_in[3];
    const float* as0  = (const float*)d_in[4];
    const float* ad0  = (const float*)d_in[5];
    const float* b0   = (const float*)d_in[6];
    const float* W1   = (const float*)d_in[7];
    const float* as1  = (const float*)d_in[8];
    const float* ad1  = (const float*)d_in[9];
    const float* b1   = (const float*)d_in[10];
    const float* Wout = (const float*)d_in[11];
    const float* bout = (const float*)d_in[12];
    float* out = (float*)d_out;

    char* p = (char*)d_ws;
    float* bufY   = (float*)p; p += (size_t)N_NODES * D_HID * sizeof(float);
    float* aS     = (float*)p; p += (size_t)N_NODES * NHEAD * sizeof(float);
    float* aD     = (float*)p; p += (size_t)N_NODES * NHEAD * sizeof(float);
    __half* bufH  = (__half*)p; p += (size_t)N_NODES * D_HID * sizeof(__half);
    int*   cnt    = (int*)p;   p += ((size_t)N_NODES + 16) * sizeof(int);
    int*   rowptr = (int*)p;   p += ((size_t)N_NODES + 16) * sizeof(int);
    int*   cursor = (int*)p;   p += ((size_t)N_NODES + 16) * sizeof(int);
    unsigned short* srclist = (unsigned short*)p; p += (size_t)N_EDGES * sizeof(unsigned short);
    int*   partials=(int*)p;   p += 256;

    int nscan = (N_NODES + 1023) / 1024;   // 49

    // 1. zero cnt (custom kernel: runtime fillBuffer measured ~41us for 200KB)
    zero_kernel<<<(N_NODES / 4 + 255) / 256, 256, 0, stream>>>((int4*)cnt, N_NODES / 4);
    // 2. hist (XCD-partitioned) + gemm0 fused by grid-slicing (independent work)
    hist_gemm_kernel<<<NHISTB + NGEMM0, 256, 0, stream>>>(
        edst, cnt, x, W0, as0, ad0, bufH, aS, aD);
    // 3-4. scan (scan2 folded into scan3)
    scan1_kernel<<<nscan, 256, 0, stream>>>(cnt, cursor, partials, N_NODES);
    scan3_kernel<<<(N_NODES + 255) / 256, 256, 0, stream>>>(cnt, cursor, partials, rowptr,
                                                            N_NODES, nscan);
    // 5. fill CSR
    fill_part_kernel<<<NHISTB, 256, 0, stream>>>(esrc, edst, cursor, srclist);
    // 6. layer-0 aggregate -> bufY
    gat_aggregate_kernel<<<(N_NODES * NHEAD + 255) / 256, 256, 0, stream>>>(
        bufH, aS, aD, rowptr, srclist, b0, bufY);
    // 7. layer-1 gemm
    gemm_alpha_kernel<<<NGEMM0, 256, 0, stream>>>(
        bufY, W1, as1, ad1, bufH, aS, aD, N_NODES, D_HID);
    // 8. layer-1 aggregate + relu + output linear + log_softmax -> out
    gat_aggregate_final_kernel<<<(N_NODES * NHEAD + 255) / 256, 256, 0, stream>>>(
        bufH, aS, aD, rowptr, srclist, b1, Wout, bout, out);
}

// Round 6
// 230.601 us; speedup vs baseline: 1.3101x; 1.0623x over previous
//
#include <hip/hip_runtime.h>
#include <hip/hip_fp16.h>
#include <math.h>

#define N_NODES 50000
#define N_EDGES 800000
#define F_IN    128
#define D_HID   96
#define NHEAD   8
#define DH      12
#define N_CLS   40
#define NEG_SLOPE 0.2f

#define NPART   (N_NODES / 8)        // 6250 dst nodes per XCD group
#define NWCHUNK 256                  // edge chunks per group
#define ECHUNK  (N_EDGES / NWCHUNK)  // 3125 edges per chunk
#define NHISTB  (8 * NWCHUNK)        // 2048 hist/fill blocks

#define BM 64
#define BK 32
#define NGEMM0  ((N_NODES + BM - 1) / BM)   // 782

// ---------------- zero cnt (custom: runtime fillBuffer is ~40us for 200KB) ----------------
__global__ __launch_bounds__(256) void zero_kernel(int4* __restrict__ p, int n4) {
    int i = blockIdx.x * blockDim.x + threadIdx.x;
    if (i < n4) p[i] = make_int4(0, 0, 0, 0);
}

// ---------------- GEMM core (A[M,K] @ W[K,96]) + per-head alpha epilogue ----------------
__device__ __forceinline__ void gemm_alpha_body(
    const float* __restrict__ A, const float* __restrict__ W,
    const float* __restrict__ asrc, const float* __restrict__ adst,
    __half* __restrict__ Hout, float* __restrict__ aS, float* __restrict__ aD,
    int M, int K, int bid,
    float (*As)[BK + 1], float (*Ws)[D_HID])
{
    int tid = threadIdx.x;
    int r   = tid & 31;
    int cg  = tid >> 5;           // head index 0..7
    int n0  = bid * BM;

    float acc[2][12];
#pragma unroll
    for (int i = 0; i < 2; i++)
#pragma unroll
        for (int j = 0; j < 12; j++) acc[i][j] = 0.f;

    int wrow = tid >> 3;
    int wcol = (tid & 7) * 12;

    for (int k0 = 0; k0 < K; k0 += BK) {
        for (int idx = tid; idx < BM * BK; idx += 256) {
            int row = idx >> 5, col = idx & 31;
            int gr = n0 + row;
            As[row][col] = (gr < M) ? A[(size_t)gr * K + k0 + col] : 0.f;
        }
        {
            const float* wp = W + (size_t)(k0 + wrow) * D_HID + wcol;
#pragma unroll
            for (int j = 0; j < 12; j++) Ws[wrow][wcol + j] = wp[j];
        }
        __syncthreads();
#pragma unroll 8
        for (int kk = 0; kk < BK; kk++) {
            float4 w0 = *(const float4*)&Ws[kk][cg * 12];
            float4 w1 = *(const float4*)&Ws[kk][cg * 12 + 4];
            float4 w2 = *(const float4*)&Ws[kk][cg * 12 + 8];
            float a0 = As[r][kk];
            float a1 = As[r + 32][kk];
            acc[0][0] += a0 * w0.x; acc[0][1] += a0 * w0.y; acc[0][2]  += a0 * w0.z; acc[0][3]  += a0 * w0.w;
            acc[0][4] += a0 * w1.x; acc[0][5] += a0 * w1.y; acc[0][6]  += a0 * w1.z; acc[0][7]  += a0 * w1.w;
            acc[0][8] += a0 * w2.x; acc[0][9] += a0 * w2.y; acc[0][10] += a0 * w2.z; acc[0][11] += a0 * w2.w;
            acc[1][0] += a1 * w0.x; acc[1][1] += a1 * w0.y; acc[1][2]  += a1 * w0.z; acc[1][3]  += a1 * w0.w;
            acc[1][4] += a1 * w1.x; acc[1][5] += a1 * w1.y; acc[1][6]  += a1 * w1.z; acc[1][7]  += a1 * w1.w;
            acc[1][8] += a1 * w2.x; acc[1][9] += a1 * w2.y; acc[1][10] += a1 * w2.z; acc[1][11] += a1 * w2.w;
        }
        __syncthreads();
    }

    float as_h[12], ad_h[12];
#pragma unroll
    for (int j = 0; j < 12; j++) { as_h[j] = asrc[cg * 12 + j]; ad_h[j] = adst[cg * 12 + j]; }

#pragma unroll
    for (int i = 0; i < 2; i++) {
        int gr = n0 + r + 32 * i;
        if (gr < M) {
            float s_ = 0.f, d_ = 0.f;
#pragma unroll
            for (int j = 0; j < 12; j++) {
                s_ += acc[i][j] * as_h[j];
                d_ += acc[i][j] * ad_h[j];
            }
            __half2* op = (__half2*)(Hout + (size_t)gr * D_HID + cg * 12);
#pragma unroll
            for (int j = 0; j < 6; j++)
                op[j] = __floats2half2_rn(acc[i][2 * j], acc[i][2 * j + 1]);
            aS[gr * NHEAD + cg] = s_;
            aD[gr * NHEAD + cg] = d_;
        }
    }
}

// ---------------- fused: hist (blocks [0,NHISTB)) + gemm0 (blocks [NHISTB,..)) ----------------
__global__ __launch_bounds__(256) void hist_gemm_kernel(
    const int* __restrict__ edst, int* __restrict__ cnt,
    const float* __restrict__ A, const float* __restrict__ W,
    const float* __restrict__ asrc, const float* __restrict__ adst,
    __half* __restrict__ Hout, float* __restrict__ aS, float* __restrict__ aD)
{
    __shared__ float As[BM][BK + 1];
    __shared__ float Ws[BK][D_HID];
    if (blockIdx.x < NHISTB) {
        int lo = (blockIdx.x & 7) * NPART;   // bid&7 == XCD (round-robin dispatch)
        int e0 = (blockIdx.x >> 3) * ECHUNK;
        for (int e = e0 + threadIdx.x; e < e0 + ECHUNK; e += 256) {
            int d = edst[e] - lo;
            if ((unsigned)d < (unsigned)NPART) atomicAdd(&cnt[lo + d], 1);
        }
    } else {
        gemm_alpha_body(A, W, asrc, adst, Hout, aS, aD, N_NODES, F_IN,
                        blockIdx.x - NHISTB, As, Ws);
    }
}

// ---------------- standalone gemm (layer 1) ----------------
__global__ __launch_bounds__(256) void gemm_alpha_kernel(
    const float* __restrict__ A, const float* __restrict__ W,
    const float* __restrict__ asrc, const float* __restrict__ adst,
    __half* __restrict__ Hout, float* __restrict__ aS, float* __restrict__ aD,
    int M, int K)
{
    __shared__ float As[BM][BK + 1];
    __shared__ float Ws[BK][D_HID];
    gemm_alpha_body(A, W, asrc, adst, Hout, aS, aD, M, K, blockIdx.x, As, Ws);
}

// ---------------- scans ----------------
__global__ void scan1_kernel(const int* __restrict__ cnt, int* __restrict__ incl,
                             int* __restrict__ partials, int n) {
    __shared__ int sdata[256];
    int t = threadIdx.x;
    int base = blockIdx.x * 1024 + t * 4;
    int v[4];
#pragma unroll
    for (int j = 0; j < 4; j++) { int i = base + j; v[j] = (i < n) ? cnt[i] : 0; }
    v[1] += v[0]; v[2] += v[1]; v[3] += v[2];
    sdata[t] = v[3];
    __syncthreads();
    for (int off = 1; off < 256; off <<= 1) {
        int x = (t >= off) ? sdata[t - off] : 0;
        __syncthreads();
        sdata[t] += x;
        __syncthreads();
    }
    int excl = sdata[t] - v[3];
#pragma unroll
    for (int j = 0; j < 4; j++) { int i = base + j; if (i < n) incl[i] = v[j] + excl; }
    if (t == 255) partials[blockIdx.x] = sdata[255];
}

// scan3 with inline prefix over raw partials (replaces scan2)
__global__ void scan3_kernel(const int* __restrict__ cnt, int* __restrict__ incl_cursor,
                             const int* __restrict__ partials, int* __restrict__ rowptr,
                             int n, int nb) {
    int i = blockIdx.x * blockDim.x + threadIdx.x;
    if (i >= n) return;
    int myb = i >> 10;
    int psum = 0;
    for (int b = 0; b < nb; b++) psum += (b < myb) ? partials[b] : 0;
    int v = incl_cursor[i] + psum;
    rowptr[i + 1] = v;
    incl_cursor[i] = v - cnt[i];
    if (i == 0) rowptr[0] = 0;
}

__global__ __launch_bounds__(256) void fill_part_kernel(
    const int* __restrict__ esrc, const int* __restrict__ edst,
    int* __restrict__ cursor, unsigned short* __restrict__ srclist)
{
    int lo = (blockIdx.x & 7) * NPART;
    int e0 = (blockIdx.x >> 3) * ECHUNK;
    for (int e = e0 + threadIdx.x; e < e0 + ECHUNK; e += 256) {
        int d = edst[e] - lo;
        if ((unsigned)d < (unsigned)NPART) {
            int p = atomicAdd(&cursor[lo + d], 1);
            srclist[p] = (unsigned short)esrc[e];
        }
    }
}

// ---------------- GAT aggregation core: thread per (node, head), single pass ----------------
__device__ __forceinline__ void agg_edge(const __half* __restrict__ h, int s, int hh,
                                         float p, float* acc) {
    const uint2* hp = (const uint2*)(h + (size_t)s * D_HID + hh * 12);
    uint2 q0 = hp[0], q1 = hp[1], q2 = hp[2];
    float2 f0 = __half22float2(((const __half2*)&q0)[0]);
    float2 f1 = __half22float2(((const __half2*)&q0)[1]);
    float2 f2 = __half22float2(((const __half2*)&q1)[0]);
    float2 f3 = __half22float2(((const __half2*)&q1)[1]);
    float2 f4 = __half22float2(((const __half2*)&q2)[0]);
    float2 f5 = __half22float2(((const __half2*)&q2)[1]);
    acc[0] += p * f0.x; acc[1]  += p * f0.y;
    acc[2] += p * f1.x; acc[3]  += p * f1.y;
    acc[4] += p * f2.x; acc[5]  += p * f2.y;
    acc[6] += p * f3.x; acc[7]  += p * f3.y;
    acc[8] += p * f4.x; acc[9]  += p * f4.y;
    acc[10] += p * f5.x; acc[11] += p * f5.y;
}

// computes o[12] = softmax-weighted sum + bias (optional relu) for (n, hh)
__device__ __forceinline__ void agg_body(
    const __half* __restrict__ h, const float* __restrict__ aS, const float* __restrict__ aD,
    const int* __restrict__ rowptr, const unsigned short* __restrict__ srclist,
    const float* __restrict__ bias, int n, int hh, int relu, float* o)
{
    int s0 = rowptr[n], s1 = rowptr[n + 1];
    float ad = aD[n * NHEAD + hh];

    float z = 0.f;
    float acc[12];
#pragma unroll
    for (int j = 0; j < 12; j++) acc[j] = 0.f;

    int i = s0;
    for (; i + 4 <= s1; i += 4) {
        int sa = srclist[i];
        int sb = srclist[i + 1];
        int sc = srclist[i + 2];
        int sd = srclist[i + 3];
        float ea = aS[sa * NHEAD + hh] + ad;
        float eb = aS[sb * NHEAD + hh] + ad;
        float ec = aS[sc * NHEAD + hh] + ad;
        float ed = aS[sd * NHEAD + hh] + ad;
        ea = (ea > 0.f) ? ea : NEG_SLOPE * ea;
        eb = (eb > 0.f) ? eb : NEG_SLOPE * eb;
        ec = (ec > 0.f) ? ec : NEG_SLOPE * ec;
        ed = (ed > 0.f) ? ed : NEG_SLOPE * ed;
        float pa = __expf(ea);
        float pb = __expf(eb);
        float pc = __expf(ec);
        float pd = __expf(ed);
        z += (pa + pb) + (pc + pd);
        agg_edge(h, sa, hh, pa, acc);
        agg_edge(h, sb, hh, pb, acc);
        agg_edge(h, sc, hh, pc, acc);
        agg_edge(h, sd, hh, pd, acc);
    }
    for (; i < s1; i++) {
        int sa = srclist[i];
        float ea = aS[sa * NHEAD + hh] + ad;
        ea = (ea > 0.f) ? ea : NEG_SLOPE * ea;
        float pa = __expf(ea);
        z += pa;
        agg_edge(h, sa, hh, pa, acc);
    }

    float inv = 1.f / (z + 1e-16f);
    const float* bp = bias + hh * 12;
#pragma unroll
    for (int j = 0; j < 12; j++) o[j] = acc[j] * inv + bp[j];
    if (relu) {
#pragma unroll
        for (int j = 0; j < 12; j++) o[j] = fmaxf(o[j], 0.f);
    }
}

// layer-0 aggregate: write bufY
__global__ __launch_bounds__(256) void gat_aggregate_kernel(
    const __half* __restrict__ h, const float* __restrict__ aS, const float* __restrict__ aD,
    const int* __restrict__ rowptr, const unsigned short* __restrict__ srclist,
    const float* __restrict__ bias, float* __restrict__ out)
{
    int gid = blockIdx.x * blockDim.x + threadIdx.x;
    if (gid >= N_NODES * NHEAD) return;
    int n  = gid >> 3;
    int hh = gid & 7;
    float o[12];
    agg_body(h, aS, aD, rowptr, srclist, bias, n, hh, 0, o);
    float4* op = (float4*)(out + (size_t)n * D_HID + hh * 12);
    op[0] = make_float4(o[0], o[1], o[2], o[3]);
    op[1] = make_float4(o[4], o[5], o[6], o[7]);
    op[2] = make_float4(o[8], o[9], o[10], o[11]);
}

// layer-1 aggregate + relu + (y @ Wout + bout) + log_softmax fused.
// All register arrays statically indexed (rule #20: runtime-indexed arrays spill
// to scratch — the previous version's part[hh*5+k] cost 64MB of spill traffic).
// Lane hh owns output columns [hh*5, hh*5+5); the node's 96-wide y vector is
// exchanged through LDS (same-wave producer/consumer, no barrier needed).
#define YPAD 100   // float4-aligned pad; ln*400B % 128 spreads 8 groups over all banks
__global__ __launch_bounds__(256) void gat_aggregate_final_kernel(
    const __half* __restrict__ h, const float* __restrict__ aS, const float* __restrict__ aD,
    const int* __restrict__ rowptr, const unsigned short* __restrict__ srclist,
    const float* __restrict__ bias,
    const float* __restrict__ Wout, const float* __restrict__ bout,
    float* __restrict__ out)
{
    __shared__ float WsT[N_CLS][YPAD];   // transposed Wout: WsT[c][r] = Wout[r*40+c]
    __shared__ float bs[N_CLS];
    __shared__ float ylds[32][YPAD];     // 32 nodes/block x 96-wide y
    for (int idx = threadIdx.x; idx < D_HID * N_CLS; idx += 256) {
        int r = idx / N_CLS, c = idx - r * N_CLS;
        WsT[c][r] = Wout[idx];
    }
    for (int idx = threadIdx.x; idx < N_CLS; idx += 256) bs[idx] = bout[idx];
    __syncthreads();

    int gid = blockIdx.x * blockDim.x + threadIdx.x;
    if (gid >= N_NODES * NHEAD) return;   // node groups of 8 never split (400000%8==0)
    int n  = gid >> 3;
    int hh = gid & 7;
    int ln = threadIdx.x >> 3;            // local node 0..31
    float o[12];
    agg_body(h, aS, aD, rowptr, srclist, bias, n, hh, 1, o);

    // publish y slice to LDS (float4 x3; same wave reads it back -> in-order DS, no barrier)
    float4* yw = (float4*)&ylds[ln][hh * 12];
    yw[0] = make_float4(o[0], o[1], o[2], o[3]);
    yw[1] = make_float4(o[4], o[5], o[6], o[7]);
    yw[2] = make_float4(o[8], o[9], o[10], o[11]);

    // res[k] = bout[c0+k] + sum_r y[r] * Wout[r][c0+k]   (all indices static)
    int c0 = hh * 5;
    float res[5];
#pragma unroll
    for (int k = 0; k < 5; k++) res[k] = bs[c0 + k];
    const float4* yr = (const float4*)&ylds[ln][0];
#pragma unroll
    for (int r4 = 0; r4 < D_HID / 4; r4++) {
        float4 yv = yr[r4];
#pragma unroll
        for (int k = 0; k < 5; k++) {
            float4 wv = *(const float4*)&WsT[c0 + k][r4 * 4];
            res[k] += yv.x * wv.x + yv.y * wv.y + yv.z * wv.z + yv.w * wv.w;
        }
    }

    // log-softmax across the 8 head-lanes (xor 1/2/4 stays within aligned 8-groups)
    float m = res[0];
#pragma unroll
    for (int k = 1; k < 5; k++) m = fmaxf(m, res[k]);
#pragma unroll
    for (int d = 1; d < 8; d <<= 1) m = fmaxf(m, __shfl_xor(m, d, 64));
    float sp = 0.f;
#pragma unroll
    for (int k = 0; k < 5; k++) sp += __expf(res[k] - m);
#pragma unroll
    for (int d = 1; d < 8; d <<= 1) sp += __shfl_xor(sp, d, 64);
    float mlg = m + __logf(sp);

    float* op = out + (size_t)n * N_CLS + c0;
#pragma unroll
    for (int k = 0; k < 5; k++) op[k] = res[k] - mlg;
}

extern "C" void kernel_launch(void* const* d_in, const int* in_sizes, int n_in,
                              void* d_out, int out_size, void* d_ws, size_t ws_size,
                              hipStream_t stream)
{
    const float* x    = (const float*)d_in[0];
    const int*   esrc = (const int*)d_in[1];
    const int*   edst = (const int*)d_in[2];
    const float* W0   = (const float*)d_in[3];
    const float* as0  = (const float*)d_in[4];
    const float* ad0  = (const float*)d_in[5];
    const float* b0   = (const float*)d_in[6];
    const float* W1   = (const float*)d_in[7];
    const float* as1  = (const float*)d_in[8];
    const float* ad1  = (const float*)d_in[9];
    const float* b1   = (const float*)d_in[10];
    const float* Wout = (const float*)d_in[11];
    const float* bout = (const float*)d_in[12];
    float* out = (float*)d_out;

    char* p = (char*)d_ws;
    float* bufY   = (float*)p; p += (size_t)N_NODES * D_HID * sizeof(float);
    float* aS     = (float*)p; p += (size_t)N_NODES * NHEAD * sizeof(float);
    float* aD     = (float*)p; p += (size_t)N_NODES * NHEAD * sizeof(float);
    __half* bufH  = (__half*)p; p += (size_t)N_NODES * D_HID * sizeof(__half);
    int*   cnt    = (int*)p;   p += ((size_t)N_NODES + 16) * sizeof(int);
    int*   rowptr = (int*)p;   p += ((size_t)N_NODES + 16) * sizeof(int);
    int*   cursor = (int*)p;   p += ((size_t)N_NODES + 16) * sizeof(int);
    unsigned short* srclist = (unsigned short*)p; p += (size_t)N_EDGES * sizeof(unsigned short);
    int*   partials=(int*)p;   p += 256;

    int nscan = (N_NODES + 1023) / 1024;   // 49

    // 1. zero cnt (custom kernel: runtime fillBuffer measured ~41us for 200KB)
    zero_kernel<<<(N_NODES / 4 + 255) / 256, 256, 0, stream>>>((int4*)cnt, N_NODES / 4);
    // 2. hist (XCD-partitioned) + gemm0 fused by grid-slicing (independent work)
    hist_gemm_kernel<<<NHISTB + NGEMM0, 256, 0, stream>>>(
        edst, cnt, x, W0, as0, ad0, bufH, aS, aD);
    // 3-4. scan (scan2 folded into scan3)
    scan1_kernel<<<nscan, 256, 0, stream>>>(cnt, cursor, partials, N_NODES);
    scan3_kernel<<<(N_NODES + 255) / 256, 256, 0, stream>>>(cnt, cursor, partials, rowptr,
                                                            N_NODES, nscan);
    // 5. fill CSR
    fill_part_kernel<<<NHISTB, 256, 0, stream>>>(esrc, edst, cursor, srclist);
    // 6. layer-0 aggregate -> bufY
    gat_aggregate_kernel<<<(N_NODES * NHEAD + 255) / 256, 256, 0, stream>>>(
        bufH, aS, aD, rowptr, srclist, b0, bufY);
    // 7. layer-1 gemm
    gemm_alpha_kernel<<<NGEMM0, 256, 0, stream>>>(
        bufY, W1, as1, ad1, bufH, aS, aD, N_NODES, D_HID);
    // 8. layer-1 aggregate + relu + output linear + log_softmax -> out
    gat_aggregate_final_kernel<<<(N_NODES * NHEAD + 255) / 256, 256, 0, stream>>>(
        bufH, aS, aD, rowptr, srclist, b1, Wout, bout, out);
}